// Round 8
// baseline (44820.859 us; speedup 1.0000x reference)
//
#include <hip/hip_runtime.h>
#include <hip/hip_bf16.h>

// ---------------------------------------------------------------------------
// Acoustic model, ws-constrained (measured ws in [2.42MB, 4.78MB) => TC=20/40).
// Pipeline per T-chunk (4 launches): pre1, pre2, enc (1 launch, internal
// b-scan with flag sync), dec (gi on-the-fly + fused post head).
// Precision: decoder recurrence H fp32 + split-A + Whh-hi (round-7 proven);
// encoder bf16 state + bf16-hi weights; out fp32.
// ---------------------------------------------------------------------------

typedef __bf16 bf16;
typedef bf16 bf16x8 __attribute__((ext_vector_type(8)));
typedef float f32x4 __attribute__((ext_vector_type(4)));

#define TLEN 800
#define BT 25600  // 32*800

__device__ __forceinline__ float bf2f(bf16 v) {
    unsigned short u = __builtin_bit_cast(unsigned short, v);
    unsigned int x = ((unsigned int)u) << 16;
    return __builtin_bit_cast(float, x);
}
__device__ __forceinline__ bf16 f2bf(float f) {
    unsigned int x = __builtin_bit_cast(unsigned int, f);
    unsigned int r = (x + 0x7FFFu + ((x >> 16) & 1u)) >> 16;
    return __builtin_bit_cast(bf16, (unsigned short)r);
}
__device__ __forceinline__ bf16x8 ld8f(const float* p) {
    f32x4 a = *(const f32x4*)p;
    f32x4 b = *(const f32x4*)(p + 4);
    bf16x8 r;
#pragma unroll
    for (int i = 0; i < 4; i++) {
        r[i] = f2bf(a[i]);
        r[i + 4] = f2bf(b[i]);
    }
    return r;
}
__device__ __forceinline__ void splitv(f32x4 a, f32x4 b, bf16x8& vh, bf16x8& vl) {
#pragma unroll
    for (int j = 0; j < 4; j++) {
        bf16 h0 = f2bf(a[j]);
        vh[j] = h0;
        vl[j] = f2bf(a[j] - bf2f(h0));
        bf16 h1 = f2bf(b[j]);
        vh[j + 4] = h1;
        vl[j + 4] = f2bf(b[j] - bf2f(h1));
    }
}
__device__ __forceinline__ f32x4 mfma16(bf16x8 a, bf16x8 b, f32x4 c) {
    return __builtin_amdgcn_mfma_f32_16x16x32_bf16(a, b, c, 0, 0, 0);
}
__device__ __forceinline__ float sigm(float x) { return 1.f / (1.f + __expf(-x)); }

// ---------------------------------------------------------------------------
// init: out = per-head bias (atomics accumulate on top), zero flags
// ---------------------------------------------------------------------------
__global__ __launch_bounds__(256) void init_k(float* __restrict__ out,
                                              const float* __restrict__ pfb,
                                              const float* __restrict__ prb,
                                              int* __restrict__ dflags,
                                              int* __restrict__ eflags, int ne) {
    int i = blockIdx.x * 256 + threadIdx.x;
    if (i < 2 * BT) out[i] = (i < BT) ? pfb[0] : prb[0];
    else if (i < 2 * BT + 1600) dflags[i - 2 * BT] = 0;
    else if (i < 2 * BT + 1600 + ne) eflags[i - 2 * BT - 1600] = 0;
}

// ---------------------------------------------------------------------------
// Prenet layer: 128x64 tile, K=256, tanh. Rows b-major m = b*TC + tt.
// MODE 0: A = note_emb[note[...]] fp32 split-A. MODE 1: A = t1 bf16.
// ---------------------------------------------------------------------------
template <int MODE>
__global__ __launch_bounds__(256) void pre_k(
    const int* __restrict__ note, const float* __restrict__ emb,
    const bf16* __restrict__ t1in, const float* __restrict__ W,
    const float* __restrict__ bias, bf16* __restrict__ out, int t0, int TC) {
    __shared__ bf16 Ah[128][72], Al[128][72], Bs[64][72];

    const int tid = threadIdx.x;
    const int lane = tid & 63, wv = tid >> 6;
    const int wm = wv & 1, wn = wv >> 1;
    const int l15 = lane & 15, hi = lane >> 4;
    const int bm = blockIdx.x * 128, bn = blockIdx.y * 64;
    const int ch = (tid & 7) * 8, arow = tid >> 3;

    f32x4 acc[4][2] = {};
    const float* ap[4];
    const bf16* tp[4];
    if (MODE == 0) {
        int zc = 0;
        for (int i = 0; i < 64; i++) zc += (note[2 * i + 1] == 0) ? 1 : 0;
        const bool n64 = (zc >= 60);
#pragma unroll
        for (int i = 0; i < 4; i++) {
            int m = bm + arow + 32 * i;
            int b = m / TC, tt = m - b * TC;
            int idx = b * TLEN + t0 + tt;
            int id = n64 ? note[2 * idx] : note[idx];
            id = id < 0 ? 0 : (id > 127 ? 127 : id);
            ap[i] = emb + (size_t)id * 256;
        }
    } else {
#pragma unroll
        for (int i = 0; i < 4; i++) tp[i] = t1in + (size_t)(bm + arow + 32 * i) * 256;
    }

    for (int k0 = 0; k0 < 256; k0 += 64) {
#pragma unroll
        for (int i = 0; i < 4; i++) {
            int row = arow + 32 * i;
            if (MODE == 0) {
                f32x4 va = *(const f32x4*)(ap[i] + k0 + ch);
                f32x4 vb = *(const f32x4*)(ap[i] + k0 + ch + 4);
                bf16x8 vh, vl;
                splitv(va, vb, vh, vl);
                *(bf16x8*)&Ah[row][ch] = vh;
                *(bf16x8*)&Al[row][ch] = vl;
            } else {
                *(bf16x8*)&Ah[row][ch] = *(const bf16x8*)(tp[i] + k0 + ch);
            }
        }
#pragma unroll
        for (int i = 0; i < 2; i++) {
            int row = arow + 32 * i;
            *(bf16x8*)&Bs[row][ch] = ld8f(W + (size_t)(bn + row) * 256 + k0 + ch);
        }
        __syncthreads();
#pragma unroll
        for (int kk = 0; kk < 64; kk += 32) {
            bf16x8 ah[4], al[4], bb[2];
#pragma unroll
            for (int mt = 0; mt < 4; mt++) {
                ah[mt] = *(const bf16x8*)&Ah[wm * 64 + mt * 16 + l15][kk + hi * 8];
                if (MODE == 0)
                    al[mt] = *(const bf16x8*)&Al[wm * 64 + mt * 16 + l15][kk + hi * 8];
            }
#pragma unroll
            for (int nt = 0; nt < 2; nt++)
                bb[nt] = *(const bf16x8*)&Bs[wn * 32 + nt * 16 + l15][kk + hi * 8];
#pragma unroll
            for (int mt = 0; mt < 4; mt++)
#pragma unroll
                for (int nt = 0; nt < 2; nt++) {
                    acc[mt][nt] = mfma16(ah[mt], bb[nt], acc[mt][nt]);
                    if (MODE == 0) acc[mt][nt] = mfma16(al[mt], bb[nt], acc[mt][nt]);
                }
        }
        __syncthreads();
    }

#pragma unroll
    for (int mt = 0; mt < 4; mt++)
#pragma unroll
        for (int nt = 0; nt < 2; nt++) {
            int n = bn + wn * 32 + nt * 16 + l15;
            float bs = bias[n];
#pragma unroll
            for (int r = 0; r < 4; r++) {
                int m = bm + wm * 64 + mt * 16 + hi * 4 + r;
                out[(size_t)m * 256 + n] = f2bf(tanhf(acc[mt][nt][r] + bs));
            }
        }
}

// ---------------------------------------------------------------------------
// Encoder: ONE launch per chunk. Grid (16 jtiles, 2 dirs, MT mtiles), all
// co-resident. Weights (96 gate-rows x 768) live in REGISTERS (no LDS).
// Internal scan over b=0..31 with per-wave agent-scope flag sync (the
// recurrence is elementwise over t-rows; only j-tiles must sync per step).
// State bf16 in ef/eb windows [b*TC+tt][512].
// ---------------------------------------------------------------------------
__global__ __launch_bounds__(256, 1) void enc_k(
    int TC, int etarget, const bf16* __restrict__ hpre, bf16* __restrict__ efb,
    bf16* __restrict__ ebb, const float* __restrict__ fWih,
    const float* __restrict__ fWhh, const float* __restrict__ fbih,
    const float* __restrict__ fbhh, const float* __restrict__ bWih,
    const float* __restrict__ bWhh, const float* __restrict__ bbih,
    const float* __restrict__ bbhh, int* __restrict__ eflg) {
    const int jtile = blockIdx.x, dir = blockIdx.y, mtile = blockIdx.z;
    const float* Wih = dir ? bWih : fWih;
    const float* Whh = dir ? bWhh : fWhh;
    const float* bih = dir ? bbih : fbih;
    const float* bhh = dir ? bbhh : fbhh;
    bf16* outb = dir ? ebb : efb;
    int* flg = eflg + dir * 32;

    const int tid = threadIdx.x;
    const int lane = tid & 63, wv = tid >> 6;
    const int mt = wv & 1, jt = wv >> 1;
    const int l15 = lane & 15, hi = lane >> 4;
    const int jb = jtile * 32 + jt * 16 + l15;

    bf16x8 Ws[3][24];  // persistent B-frags: 288 VGPRs
#pragma unroll
    for (int s = 0; s < 3; s++) {
        int wr = s * 512 + jb;
#pragma unroll
        for (int kb = 0; kb < 24; kb++) {
            int k = kb * 32 + hi * 8;
            Ws[s][kb] = (k < 256) ? ld8f(Wih + (size_t)wr * 256 + k)
                                  : ld8f(Whh + (size_t)wr * 512 + (k - 256));
        }
    }
    const float bir = bih[jb] + bhh[jb];
    const float biz = bih[512 + jb] + bhh[512 + jb];
    const float bin = bih[1024 + jb];
    const float bhn = bhh[1024 + jb];
    const int art = mtile * 32 + mt * 16 + l15;
    const int tcl = art < TC ? art : TC - 1;

    for (int step = 0; step < 32; step++) {
        const int bsrc = dir ? 31 - step : step;
        const int prevb = dir ? 32 - step : step - 1;
        if (step > 0) {
            while (__hip_atomic_load(&flg[step - 1], __ATOMIC_RELAXED,
                                     __HIP_MEMORY_SCOPE_AGENT) < etarget)
                __builtin_amdgcn_s_sleep(1);
            __builtin_amdgcn_fence(__ATOMIC_ACQUIRE, "agent");
        }
        f32x4 ar = {}, az = {}, ai = {}, ah = {};
        const bf16* xrow = hpre + ((size_t)bsrc * TC + tcl) * 256;
#pragma unroll
        for (int kb = 0; kb < 8; kb++) {
            bf16x8 a = *(const bf16x8*)(xrow + kb * 32 + hi * 8);
            ar = mfma16(a, Ws[0][kb], ar);
            az = mfma16(a, Ws[1][kb], az);
            ai = mfma16(a, Ws[2][kb], ai);
        }
        if (step > 0) {
            const bf16* hrow = outb + ((size_t)prevb * TC + tcl) * 512;
#pragma unroll
            for (int kb = 8; kb < 24; kb++) {
                bf16x8 a = *(const bf16x8*)(hrow + (kb - 8) * 32 + hi * 8);
                ar = mfma16(a, Ws[0][kb], ar);
                az = mfma16(a, Ws[1][kb], az);
                ah = mfma16(a, Ws[2][kb], ah);
            }
        }
#pragma unroll
        for (int r = 0; r < 4; r++) {
            int trow = mtile * 32 + mt * 16 + hi * 4 + r;
            if (trow < TC) {
                float rr = sigm(ar[r] + bir), zz = sigm(az[r] + biz);
                float hpv =
                    (step > 0) ? bf2f(outb[((size_t)prevb * TC + trow) * 512 + jb]) : 0.f;
                float nn = tanhf(ai[r] + bin + rr * (ah[r] + bhn));
                outb[((size_t)bsrc * TC + trow) * 512 + jb] = f2bf((1.f - zz) * nn + zz * hpv);
            }
        }
        __threadfence();
        if (lane == 0)
            __hip_atomic_fetch_add(&flg[step], 1, __ATOMIC_RELEASE,
                                   __HIP_MEMORY_SCOPE_AGENT);
    }
}

// ---------------------------------------------------------------------------
// Decoder: ONE launch per chunk. Grid (32 j-slices x 2 decoders) = 64 WGs.
// Per WG: 16 j-cols. gi computed on the fly (Wih: 20 k-blocks LDS bf16 +
// 14 streamed from L2); gh: Whh-hi in regs, H fp32 2-slot ring, split-A.
// Post head fused: shuffle-reduce + atomicAdd onto bias-initialized out.
// Only wave 0 computes (mt-merged tiles: B-frag reuse across both b-halves).
// ---------------------------------------------------------------------------
__global__ __launch_bounds__(256, 1) void dec_k(
    const bf16* __restrict__ ef, const bf16* __restrict__ eb,
    const float* __restrict__ sigF, const float* __restrict__ sigR,
    const float* __restrict__ fWih, const float* __restrict__ fWhh,
    const float* __restrict__ fbih, const float* __restrict__ fbhh,
    const float* __restrict__ rWih, const float* __restrict__ rWhh,
    const float* __restrict__ rbih, const float* __restrict__ rbhh,
    const float* __restrict__ f0W_, const float* __restrict__ f0b_,
    const float* __restrict__ rmW_, const float* __restrict__ rmb_,
    const float* __restrict__ pfW, const float* __restrict__ prW,
    float* __restrict__ Hring, float* __restrict__ out, int* __restrict__ dflags,
    int t0, int TC) {
    __shared__ bf16 WiS[48][648];  // 62,208 B: Wih k-blocks 0..19 (cols 0..639)

    const int g = blockIdx.x;  // 0..31: j-slice of 16
    const int d = blockIdx.y;
    const float* Wih = d ? rWih : fWih;
    const float* Whh = d ? rWhh : fWhh;
    const float* bih = d ? rbih : fbih;
    const float* bhh = d ? rbhh : fbhh;
    const float* sig = d ? sigR : sigF;
    const float* fwp = d ? rmW_ : f0W_;
    const float* fbp = d ? rmb_ : f0b_;
    const float* pW = d ? prW : pfW;
    float* Hr = Hring + (size_t)d * 2 * 16384;
    int* flg = dflags + d * TLEN;

    const int tid = threadIdx.x;
    // cooperative LDS stage: 48 rows x 640 cols
    for (int it = 0; it < 15; it++) {
        int idx = tid + 256 * it;
        int row = idx / 80, cc = (idx % 80) * 8;
        int wr = (row >> 4) * 512 + g * 16 + (row & 15);
        *(bf16x8*)&WiS[row][cc] = ld8f(Wih + (size_t)wr * 1088 + cc);
    }
    __syncthreads();
    if (tid >= 64) return;  // wave 0 only from here

    const int lane = tid;
    const int l15 = lane & 15, hi = lane >> 4;
    const int j_abs = g * 16 + l15;

    bf16x8 Wh[3][16];
#pragma unroll
    for (int s = 0; s < 3; s++)
#pragma unroll
        for (int kb = 0; kb < 16; kb++)
            Wh[s][kb] = ld8f(Whh + (size_t)(s * 512 + j_abs) * 512 + kb * 32 + hi * 8);

    f32x4 fwv[2][2], fbb[2][2];
#pragma unroll
    for (int q = 0; q < 2; q++) {
        int off = q * 32 + hi * 8;
        fwv[q][0] = *(const f32x4*)(fwp + off);
        fwv[q][1] = *(const f32x4*)(fwp + off + 4);
        fbb[q][0] = *(const f32x4*)(fbp + off);
        fbb[q][1] = *(const f32x4*)(fbp + off + 4);
    }
    const float brc = bih[j_abs] + bhh[j_abs];
    const float bzc = bih[512 + j_abs] + bhh[512 + j_abs];
    const float bin = bih[1024 + j_abs];
    const float bhn = bhh[1024 + j_abs];
    const float pw = pW[j_abs];

    for (int tt = 0; tt < TC; tt++) {
        const int t = t0 + tt;
        const float sv0 = sig[(size_t)l15 * TLEN + t];
        const float sv1 = sig[(size_t)(16 + l15) * TLEN + t];
        f32x4 ar0 = {}, ar1 = {}, az0 = {}, az1 = {}, ai0 = {}, ai1 = {},
              ah0 = {}, ah1 = {};
        // gi (flag-independent: computed before the spin)
        for (int kb = 0; kb < 34; kb++) {
            bf16x8 a0, a1;
            if (kb < 16) {
                a0 = *(const bf16x8*)(ef + ((size_t)l15 * TC + tt) * 512 + kb * 32 + hi * 8);
                a1 = *(const bf16x8*)(ef + ((size_t)(16 + l15) * TC + tt) * 512 + kb * 32 + hi * 8);
            } else if (kb < 32) {
                a0 = *(const bf16x8*)(eb + ((size_t)l15 * TC + tt) * 512 + (kb - 16) * 32 + hi * 8);
                a1 = *(const bf16x8*)(eb + ((size_t)(16 + l15) * TC + tt) * 512 + (kb - 16) * 32 + hi * 8);
            } else {
                int q = kb - 32;
#pragma unroll
                for (int j2 = 0; j2 < 4; j2++) {
                    a0[j2] = f2bf(sv0 * fwv[q][0][j2] + fbb[q][0][j2]);
                    a0[4 + j2] = f2bf(sv0 * fwv[q][1][j2] + fbb[q][1][j2]);
                    a1[j2] = f2bf(sv1 * fwv[q][0][j2] + fbb[q][0][j2]);
                    a1[4 + j2] = f2bf(sv1 * fwv[q][1][j2] + fbb[q][1][j2]);
                }
            }
            bf16x8 b0, b1, b2;
            if (kb < 20) {
                b0 = *(const bf16x8*)&WiS[l15][kb * 32 + hi * 8];
                b1 = *(const bf16x8*)&WiS[16 + l15][kb * 32 + hi * 8];
                b2 = *(const bf16x8*)&WiS[32 + l15][kb * 32 + hi * 8];
            } else {
                b0 = ld8f(Wih + (size_t)j_abs * 1088 + kb * 32 + hi * 8);
                b1 = ld8f(Wih + (size_t)(512 + j_abs) * 1088 + kb * 32 + hi * 8);
                b2 = ld8f(Wih + (size_t)(1024 + j_abs) * 1088 + kb * 32 + hi * 8);
            }
            ar0 = mfma16(a0, b0, ar0);
            ar1 = mfma16(a1, b0, ar1);
            az0 = mfma16(a0, b1, az0);
            az1 = mfma16(a1, b1, az1);
            ai0 = mfma16(a0, b2, ai0);
            ai1 = mfma16(a1, b2, ai1);
        }
        float hp0[4] = {0.f, 0.f, 0.f, 0.f}, hp1[4] = {0.f, 0.f, 0.f, 0.f};
        if (t > 0) {
            while (__hip_atomic_load(&flg[t - 1], __ATOMIC_RELAXED,
                                     __HIP_MEMORY_SCOPE_AGENT) < 32)
                __builtin_amdgcn_s_sleep(1);
            __builtin_amdgcn_fence(__ATOMIC_ACQUIRE, "agent");
            const float* Hp = Hr + ((t - 1) & 1) * 16384;
            const float* ap0 = Hp + (size_t)l15 * 512 + hi * 8;
            const float* ap1 = Hp + (size_t)(16 + l15) * 512 + hi * 8;
#pragma unroll
            for (int kb = 0; kb < 16; kb++) {
                bf16x8 h0h, h0l, h1h, h1l;
                {
                    f32x4 x = *(const f32x4*)(ap0 + kb * 32);
                    f32x4 y = *(const f32x4*)(ap0 + kb * 32 + 4);
                    splitv(x, y, h0h, h0l);
                }
                {
                    f32x4 x = *(const f32x4*)(ap1 + kb * 32);
                    f32x4 y = *(const f32x4*)(ap1 + kb * 32 + 4);
                    splitv(x, y, h1h, h1l);
                }
                ar0 = mfma16(h0h, Wh[0][kb], ar0);
                ar0 = mfma16(h0l, Wh[0][kb], ar0);
                ar1 = mfma16(h1h, Wh[0][kb], ar1);
                ar1 = mfma16(h1l, Wh[0][kb], ar1);
                az0 = mfma16(h0h, Wh[1][kb], az0);
                az0 = mfma16(h0l, Wh[1][kb], az0);
                az1 = mfma16(h1h, Wh[1][kb], az1);
                az1 = mfma16(h1l, Wh[1][kb], az1);
                ah0 = mfma16(h0h, Wh[2][kb], ah0);
                ah0 = mfma16(h0l, Wh[2][kb], ah0);
                ah1 = mfma16(h1h, Wh[2][kb], ah1);
                ah1 = mfma16(h1l, Wh[2][kb], ah1);
            }
#pragma unroll
            for (int r = 0; r < 4; r++) {
                hp0[r] = Hp[(size_t)(hi * 4 + r) * 512 + j_abs];
                hp1[r] = Hp[(size_t)(16 + hi * 4 + r) * 512 + j_abs];
            }
        }
        float* Hc = Hr + (t & 1) * 16384;
#pragma unroll
        for (int r = 0; r < 4; r++) {
            {
                float rr = sigm(ar0[r] + brc), zz = sigm(az0[r] + bzc);
                float nn = tanhf(ai0[r] + bin + rr * (ah0[r] + bhn));
                float hn = (1.f - zz) * nn + zz * hp0[r];
                Hc[(size_t)(hi * 4 + r) * 512 + j_abs] = hn;
                float p = hn * pw;
                p += __shfl_xor(p, 1);
                p += __shfl_xor(p, 2);
                p += __shfl_xor(p, 4);
                p += __shfl_xor(p, 8);
                if (l15 == 0) atomicAdd(out + (size_t)d * BT + (hi * 4 + r) * TLEN + t, p);
            }
            {
                float rr = sigm(ar1[r] + brc), zz = sigm(az1[r] + bzc);
                float nn = tanhf(ai1[r] + bin + rr * (ah1[r] + bhn));
                float hn = (1.f - zz) * nn + zz * hp1[r];
                Hc[(size_t)(16 + hi * 4 + r) * 512 + j_abs] = hn;
                float p = hn * pw;
                p += __shfl_xor(p, 1);
                p += __shfl_xor(p, 2);
                p += __shfl_xor(p, 4);
                p += __shfl_xor(p, 8);
                if (l15 == 0)
                    atomicAdd(out + (size_t)d * BT + (16 + hi * 4 + r) * TLEN + t, p);
            }
        }
        __threadfence();
        if (lane == 0)
            __hip_atomic_fetch_add(&flg[t], 1, __ATOMIC_RELEASE,
                                   __HIP_MEMORY_SCOPE_AGENT);
    }
}

// ---------------------------------------------------------------------------
extern "C" void kernel_launch(void* const* d_in, const int* in_sizes, int n_in,
                              void* d_out, int out_size, void* d_ws, size_t ws_size,
                              hipStream_t stream) {
    const int* note = (const int*)d_in[0];
    const float* f0_prev = (const float*)d_in[1];
    const float* rmse_prev = (const float*)d_in[2];
    const float* note_emb = (const float*)d_in[3];
    const float* f0_W = (const float*)d_in[4];
    const float* f0_b = (const float*)d_in[5];
    const float* rmse_W = (const float*)d_in[6];
    const float* rmse_b = (const float*)d_in[7];
    const float* pre1_W = (const float*)d_in[8];
    const float* pre1_b = (const float*)d_in[9];
    const float* pre2_W = (const float*)d_in[10];
    const float* pre2_b = (const float*)d_in[11];
    const float* encf_Wih = (const float*)d_in[12];
    const float* encf_Whh = (const float*)d_in[13];
    const float* encf_bih = (const float*)d_in[14];
    const float* encf_bhh = (const float*)d_in[15];
    const float* encb_Wih = (const float*)d_in[16];
    const float* encb_Whh = (const float*)d_in[17];
    const float* encb_bih = (const float*)d_in[18];
    const float* encb_bhh = (const float*)d_in[19];
    const float* decf_Wih = (const float*)d_in[20];
    const float* decf_Whh = (const float*)d_in[21];
    const float* decf_bih = (const float*)d_in[22];
    const float* decf_bhh = (const float*)d_in[23];
    const float* decr_Wih = (const float*)d_in[24];
    const float* decr_Whh = (const float*)d_in[25];
    const float* decr_bih = (const float*)d_in[26];
    const float* decr_bhh = (const float*)d_in[27];
    const float* postf_W = (const float*)d_in[28];
    const float* postf_b = (const float*)d_in[29];
    const float* postr_W = (const float*)d_in[30];
    const float* postr_b = (const float*)d_in[31];
    float* out = (float*)d_out;

    // TC selection: per-TC bytes = ef+eb (2*32768) + hpre+t1 (2*16384) = 98304
    const int tcs[4] = {40, 20, 8, 4};
    int TC = 4;
    for (int i = 0; i < 4; i++) {
        int tc = tcs[i];
        size_t need = (size_t)98304 * tc + 262144 + 6400 + (size_t)256 * (TLEN / tc) + 4096;
        if (ws_size >= need) { TC = tc; break; }
    }
    const int NC = TLEN / TC;
    const int MT = (TC + 31) / 32;
    const int etarget = 64 * MT;

    char* ws = (char*)d_ws;
    size_t off = 0;
    auto carve = [&](size_t bytes) {
        void* p = ws + off;
        off += (bytes + 255) & ~(size_t)255;
        return p;
    };
    bf16* ef_c = (bf16*)carve((size_t)32768 * TC);
    bf16* eb_c = (bf16*)carve((size_t)32768 * TC);
    bf16* hpre_c = (bf16*)carve((size_t)16384 * TC);
    bf16* t1_c = (bf16*)carve((size_t)16384 * TC);
    float* Hring = (float*)carve(262144);   // 2 dec x 2 slots x 32x512 fp32
    int* dflags = (int*)carve(6400);        // 2 x 800
    int* eflags = (int*)carve((size_t)256 * NC);  // NC x 2 x 32

    const int ne = 64 * NC;
    init_k<<<dim3((2 * BT + 1600 + ne + 255) / 256), 256, 0, stream>>>(
        out, postf_b, postr_b, dflags, eflags, ne);

    for (int c = 0; c < NC; c++) {
        const int t0 = c * TC;
        pre_k<0><<<dim3(TC / 4, 4), 256, 0, stream>>>(note, note_emb, nullptr, pre1_W,
                                                      pre1_b, t1_c, t0, TC);
        pre_k<1><<<dim3(TC / 4, 4), 256, 0, stream>>>(nullptr, nullptr, t1_c, pre2_W,
                                                      pre2_b, hpre_c, t0, TC);
        enc_k<<<dim3(16, 2, MT), 256, 0, stream>>>(
            TC, etarget, hpre_c, ef_c, eb_c, encf_Wih, encf_Whh, encf_bih, encf_bhh,
            encb_Wih, encb_Whh, encb_bih, encb_bhh, eflags + c * 64);
        dec_k<<<dim3(32, 2), 256, 0, stream>>>(
            ef_c, eb_c, f0_prev, rmse_prev, decf_Wih, decf_Whh, decf_bih, decf_bhh,
            decr_Wih, decr_Whh, decr_bih, decr_bhh, f0_W, f0_b, rmse_W, rmse_b,
            postf_W, postr_W, Hring, out, dflags, t0, TC);
    }
    (void)in_sizes; (void)n_in; (void)out_size; (void)ws_size;
}